// Round 7
// baseline (1854.554 us; speedup 1.0000x reference)
//
#include <hip/hip_runtime.h>
#include <cstddef>
#include <cstdint>

#define NN 20000
#define EE 160000
#define EPRIME 180000   // EE + NN (self loops)
#define GG 128
#define FF 114
#define HH 10
#define HFD 1140        // FF*HH
#define KP 1152         // padded feature dim (36*32, 9*128)
#define F1K 2280        // fcg1 K
#define F1KS 18         // split-K chunks
#define F1KC 128        // chunk size
#define NSCB 79         // scan blocks = cdiv(NN,256)

typedef unsigned short ushort_t;
typedef __attribute__((ext_vector_type(8))) short bf16x8;
typedef __attribute__((ext_vector_type(4))) float f32x4;

static inline int cdiv(int a, int b) { return (a + b - 1) / b; }

// ---------------- bf16 helpers ----------------

__device__ __forceinline__ ushort_t f2bf(float v) {
    union { float f; unsigned u; } c; c.f = v;
    unsigned u = c.u;
    unsigned r = (u + 0x7fffu + ((u >> 16) & 1u)) >> 16;   // RNE
    return (ushort_t)r;
}
__device__ __forceinline__ float bf2f(ushort_t h) {
    union { unsigned u; float f; } c; c.u = ((unsigned)h) << 16;
    return c.f;
}

__device__ __forceinline__ void gload16(const void* g, const ushort_t* l) {
    __builtin_amdgcn_global_load_lds(
        (const __attribute__((address_space(1))) unsigned int*)g,
        (__attribute__((address_space(3))) unsigned int*)l, 16, 0, 0);
}

// ---------------- CSR construction ----------------

__global__ void k_init(int* __restrict__ deg, int* __restrict__ gstart, int* __restrict__ gend) {
    int i = blockIdx.x * blockDim.x + threadIdx.x;
    if (i < NN) deg[i] = 1;               // self loop
    if (i < GG) { gstart[i] = NN; gend[i] = 0; }
}

__global__ void k_count(const int* __restrict__ ei, int* __restrict__ deg) {
    int i = blockIdx.x * blockDim.x + threadIdx.x;
    if (i < EE) atomicAdd(&deg[ei[EE + i]], 1);
}

// hierarchical scan: per-block inclusive + block totals
__global__ void k_scan1(const int* __restrict__ deg, int* __restrict__ offs, int* __restrict__ bsum) {
    __shared__ int tmp[256];
    int b = blockIdx.x, tid = threadIdx.x;
    int i = b * 256 + tid;
    int v = (i < NN) ? deg[i] : 0;
    tmp[tid] = v;
    __syncthreads();
#pragma unroll
    for (int off = 1; off < 256; off <<= 1) {
        int t = (tid >= off) ? tmp[tid - off] : 0;
        __syncthreads();
        tmp[tid] += t;
        __syncthreads();
    }
    if (i < NN) offs[i + 1] = tmp[tid];
    if (tid == 255) bsum[b] = tmp[255];
}

__global__ void k_scan2(int* __restrict__ bsum) {
    __shared__ int tmp[128];
    int tid = threadIdx.x;
    int v = (tid < NSCB) ? bsum[tid] : 0;
    tmp[tid] = v;
    __syncthreads();
#pragma unroll
    for (int off = 1; off < 128; off <<= 1) {
        int t = (tid >= off) ? tmp[tid - off] : 0;
        __syncthreads();
        tmp[tid] += t;
        __syncthreads();
    }
    if (tid < NSCB) bsum[tid] = tmp[tid] - v;   // exclusive prefix
}

// fused: finalize offs + cursor + dinv + graph ranges
__global__ void k_scan3prep(int* __restrict__ offs, const int* __restrict__ bsum,
                            int* __restrict__ cursor, const int* __restrict__ deg,
                            float* __restrict__ dinv, const int* __restrict__ batch,
                            int* __restrict__ gstart, int* __restrict__ gend) {
    int i = blockIdx.x * 256 + threadIdx.x;
    if (i < NN) {
        int o = offs[i + 1] + bsum[i >> 8];   // inclusive prefix up to i
        offs[i + 1] = o;
        cursor[i] = o - deg[i];               // exclusive prefix = offs[i]
        dinv[i] = rsqrtf((float)deg[i]);
        int b = batch[i];
        atomicMin(&gstart[b], i);
        atomicMax(&gend[b], i + 1);
    }
    if (i == 0) offs[0] = 0;
}

__global__ void k_fill(const int* __restrict__ ei, int* __restrict__ cursor, int* __restrict__ csr) {
    int i = blockIdx.x * blockDim.x + threadIdx.x;
    if (i < EPRIME) {
        int s, d;
        if (i < EE) { s = ei[i]; d = ei[EE + i]; }
        else        { s = i - EE; d = s; }
        int pos = atomicAdd(&cursor[d], 1);
        csr[pos] = s;
    }
}

// ---------------- split / transpose-split conversions ----------------

__global__ void k_split_x(const float* __restrict__ x, ushort_t* __restrict__ xhi, ushort_t* __restrict__ xlo) {
    int idx = blockIdx.x * 256 + threadIdx.x;
    if (idx >= NN * 128) return;
    int n = idx >> 7, k = idx & 127;
    float v = (k < FF) ? x[(size_t)n * FF + k] : 0.f;
    ushort_t hi = f2bf(v);
    ushort_t lo = f2bf(v - bf2f(hi));
    xhi[idx] = hi; xlo[idx] = lo;
}

// W [K,Nc] -> T[n][k]=W[k][n], split bf16, zero pad. Coalesced via LDS 64x64 tiles.
__global__ __launch_bounds__(256) void k_tsplitT(const float* __restrict__ W, int K, int Nc,
                                                 int Kpad, ushort_t* __restrict__ Thi,
                                                 ushort_t* __restrict__ Tlo) {
    __shared__ float tile[64][65];
    int kb = blockIdx.x * 64;
    int nb = blockIdx.y * 64;
    int c = threadIdx.x & 63, r4 = threadIdx.x >> 6;
#pragma unroll
    for (int rr = 0; rr < 16; ++rr) {
        int r = r4 * 16 + rr;
        int gk = kb + r, gn = nb + c;
        tile[r][c] = (gk < K && gn < Nc) ? W[(size_t)gk * Nc + gn] : 0.f;
    }
    __syncthreads();
#pragma unroll
    for (int rr = 0; rr < 16; ++rr) {
        int r = r4 * 16 + rr;
        int gn = nb + r, gk = kb + c;
        float v = tile[c][r];
        ushort_t hi = f2bf(v);
        ushort_t lo = f2bf(v - bf2f(hi));
        size_t o = (size_t)gn * Kpad + gk;
        Thi[o] = hi; Tlo[o] = lo;
    }
}

// ---------------- split-bf16 MFMA GEMM: A via LDS dbuf, B direct global->reg ----------------
// C[M x Nreal] = (Ahi+Alo)[M x K] @ (Bthi+Btlo)^T   (Bt stored [Npad][Kpad])
// LDS-BW diagnosis (round 6): A+B staged = 96KB LDS traffic per 192 MFMA -> LDS-bound at ~27%
// MfmaUtil. B fragments are contiguous 16B in the [col][k] layout -> load them straight to
// VGPRs from L2 (B panel 1.2MB/col-block, L2-resident via XCD swizzle). LDS now A-only:
// 48KB per 192 MFMA. vmcnt(0) before barrier only drains the A-stage (B(k) retired pre-MFMA).

template <int OUTMODE>
__global__ __launch_bounds__(256) void mfma_gemm(
    const ushort_t* __restrict__ Ahi, const ushort_t* __restrict__ Alo,
    const ushort_t* __restrict__ Bthi, const ushort_t* __restrict__ Btlo,
    int lda, int ldb, int M, int Nreal, int ksteps, int ncb,
    float* __restrict__ C, int ldc,
    ushort_t* __restrict__ Chi, ushort_t* __restrict__ Clo, int ldcs) {
    __shared__ __align__(16) ushort_t lds[2 * 8192];   // 2 bufs x (Ahi[4kg][128r][8] | Alo ...)
    const int tid = threadIdx.x;
    const int lane = tid & 63;
    const int w = tid >> 6;
    const int wr = w >> 1, wc = w & 1;

    // bijective XCD-chunked swizzle (m204)
    int nwg = gridDim.x;
    int q = nwg >> 3, r8 = nwg & 7;
    int xcd = blockIdx.x & 7, sidx = blockIdx.x >> 3;
    int wg = (xcd < r8 ? xcd * (q + 1) : r8 * (q + 1) + (xcd - r8) * q) + sidx;
    int brow = wg / ncb, bcol = wg - brow * ncb;

    int row0 = brow * 128; if (row0 > M - 128) row0 = M - 128;   // overlap trick, idempotent writes
    const int col0 = bcol * 128;

    f32x4 acc[4][4];
#pragma unroll
    for (int i = 0; i < 4; ++i)
#pragma unroll
        for (int j = 0; j < 4; ++j) acc[i][j] = (f32x4){0.f, 0.f, 0.f, 0.f};

    const size_t ldaB = (size_t)lda * 2;
    const char* pA[4];
    unsigned ldst[4];
#pragma unroll
    for (int l = 0; l < 4; ++l) {
        int c = l * 256 + tid;            // 16B chunk id 0..1023
        if (c < 512) { int kg = c >> 7, r = c & 127;
                       pA[l] = (const char*)Ahi + (size_t)(row0 + r) * ldaB + kg * 16; }
        else         { int cc = c - 512; int kg = cc >> 7, r = cc & 127;
                       pA[l] = (const char*)Alo + (size_t)(row0 + r) * ldaB + kg * 16; }
        ldst[l] = (unsigned)c * 8;        // ushort offset within buffer
    }
    const int kgf = lane >> 4, r15 = lane & 15;

    // per-lane B element offsets (ushorts), step-invariant part
    size_t boff[4];
#pragma unroll
    for (int j = 0; j < 4; ++j)
        boff[j] = (size_t)(col0 + wc * 64 + j * 16 + r15) * ldb + kgf * 8;

    auto STAGE = [&](int buf, int ks) {
        size_t kb = (size_t)ks * 64;      // bytes (32 elems * 2B)
        const ushort_t* base = lds + buf * 8192;
#pragma unroll
        for (int l = 0; l < 4; ++l) gload16(pA[l] + kb, base + ldst[l]);
    };

    STAGE(0, 0);
    asm volatile("s_waitcnt vmcnt(0)" ::: "memory");
    __syncthreads();
    int cur = 0;

    for (int ks = 0; ks < ksteps; ++ks) {
        int kso = ks * 32;
        // B fragments straight from global (L2-resident panel)
        bf16x8 bh[4], bl[4];
#pragma unroll
        for (int j = 0; j < 4; ++j) {
            bh[j] = *(const bf16x8*)(Bthi + boff[j] + kso);
            bl[j] = *(const bf16x8*)(Btlo + boff[j] + kso);
        }
        if (ks + 1 < ksteps) STAGE(cur ^ 1, ks + 1);   // prefetch next A tile
        const ushort_t* lb = lds + cur * 8192;
        bf16x8 ah[4], al[4];
#pragma unroll
        for (int i = 0; i < 4; ++i) {
            int ra = wr * 64 + i * 16 + r15;
            ah[i] = *(const bf16x8*)(lb + kgf * 1024 + ra * 8);
            al[i] = *(const bf16x8*)(lb + 4096 + kgf * 1024 + ra * 8);
        }
#pragma unroll
        for (int i = 0; i < 4; ++i)
#pragma unroll
            for (int j = 0; j < 4; ++j) {
                acc[i][j] = __builtin_amdgcn_mfma_f32_16x16x32_bf16(ah[i], bh[j], acc[i][j], 0, 0, 0);
                acc[i][j] = __builtin_amdgcn_mfma_f32_16x16x32_bf16(ah[i], bl[j], acc[i][j], 0, 0, 0);
                acc[i][j] = __builtin_amdgcn_mfma_f32_16x16x32_bf16(al[i], bh[j], acc[i][j], 0, 0, 0);
            }
        asm volatile("s_waitcnt vmcnt(0)" ::: "memory");
        __syncthreads();
        cur ^= 1;
    }

    const int g4 = lane >> 4;
#pragma unroll
    for (int i = 0; i < 4; ++i)
#pragma unroll
        for (int j = 0; j < 4; ++j) {
            int c = col0 + wc * 64 + j * 16 + r15;
#pragma unroll
            for (int reg = 0; reg < 4; ++reg) {
                int r = row0 + wr * 64 + i * 16 + g4 * 4 + reg;
                float v = acc[i][j][reg];
                if (OUTMODE == 0) {
                    if (r < M && c < Nreal) C[(size_t)r * ldc + c] = v;
                } else {
                    if (r < M) {
                        if (c >= Nreal) v = 0.f;
                        ushort_t hi = f2bf(v);
                        ushort_t lo = f2bf(v - bf2f(hi));
                        Chi[(size_t)r * ldcs + c] = hi;
                        Clo[(size_t)r * ldcs + c] = lo;
                    }
                }
            }
        }
}

// ---------------- attention logits from split h0 ----------------

__global__ void k_att(const ushort_t* __restrict__ h0hi, const ushort_t* __restrict__ h0lo,
                      const float* __restrict__ att_src, const float* __restrict__ att_dst,
                      float* __restrict__ as_, float* __restrict__ ad_) {
    int id = blockIdx.x * blockDim.x + threadIdx.x;
    if (id >= NN * HH) return;
    int n = id / HH, h = id % HH;
    const ushort_t* rh = h0hi + (size_t)n * KP + h * FF;
    const ushort_t* rl = h0lo + (size_t)n * KP + h * FF;
    const float* ws = att_src + h * FF;
    const float* wd = att_dst + h * FF;
    float as = 0.f, ad = 0.f;
    for (int f = 0; f < FF; f += 2) {
        unsigned vh = *(const unsigned*)(rh + f);
        unsigned vl = *(const unsigned*)(rl + f);
        float v0 = bf2f((ushort_t)(vh & 0xffffu)) + bf2f((ushort_t)(vl & 0xffffu));
        float v1 = bf2f((ushort_t)(vh >> 16)) + bf2f((ushort_t)(vl >> 16));
        as += v0 * ws[f] + v1 * ws[f + 1];
        ad += v0 * wd[f] + v1 * wd[f + 1];
    }
    as_[id] = as;
    ad_[id] = ad;
}

// ---------------- GAT aggregation: one wave per dst node, 2-edge unrolled ----------------
// softmax WITHOUT max-subtraction (shift-invariant; logits are O(1))

__global__ __launch_bounds__(256) void gat_agg(
    const ushort_t* __restrict__ h0hi, const ushort_t* __restrict__ h0lo,
    const float* __restrict__ as_, const float* __restrict__ ad_,
    const int* __restrict__ offs, const int* __restrict__ csr,
    const float* __restrict__ bias,
    ushort_t* __restrict__ outhi, ushort_t* __restrict__ outlo) {
    int lane = threadIdx.x & 63;
    int n = blockIdx.x * 4 + (threadIdx.x >> 6);
    if (n >= NN) return;
    int beg = offs[n], end = offs[n + 1];
    float my_ad = (lane < HH) ? ad_[n * HH + lane] : 0.f;

    int hd[5][4];
#pragma unroll
    for (int j = 0; j < 5; ++j)
#pragma unroll
        for (int e = 0; e < 4; ++e) {
            int k = 4 * (lane + 64 * j) + e;
            hd[j][e] = (k < HFD) ? (k / FF) : 0;
        }

    float den = 0.f;
    float acc[5][4];
#pragma unroll
    for (int j = 0; j < 5; ++j)
#pragma unroll
        for (int e = 0; e < 4; ++e) acc[j][e] = 0.f;

    int eg = beg;
    for (; eg + 2 <= end; eg += 2) {
        int s0 = csr[eg], s1 = csr[eg + 1];
        float ex0 = 0.f, ex1 = 0.f;
        if (lane < HH) {
            float t0 = as_[s0 * HH + lane] + my_ad; t0 = (t0 >= 0.f) ? t0 : 0.2f * t0;
            float t1 = as_[s1 * HH + lane] + my_ad; t1 = (t1 >= 0.f) ? t1 : 0.2f * t1;
            ex0 = __expf(t0); ex1 = __expf(t1);
            den += ex0 + ex1;
        }
        const ushort_t* hh0 = h0hi + (size_t)s0 * KP;
        const ushort_t* hl0 = h0lo + (size_t)s0 * KP;
        const ushort_t* hh1 = h0hi + (size_t)s1 * KP;
        const ushort_t* hl1 = h0lo + (size_t)s1 * KP;
#pragma unroll
        for (int j = 0; j < 4; ++j) {
            int m = lane + 64 * j;
            uint2 a0 = *(const uint2*)(hh0 + 4 * m), b0 = *(const uint2*)(hl0 + 4 * m);
            uint2 a1 = *(const uint2*)(hh1 + 4 * m), b1 = *(const uint2*)(hl1 + 4 * m);
#pragma unroll
            for (int e = 0; e < 4; ++e) {
                unsigned ua = (e < 2) ? a0.x : a0.y, ub = (e < 2) ? b0.x : b0.y;
                unsigned va = (e < 2) ? a1.x : a1.y, vb = (e < 2) ? b1.x : b1.y;
                ushort_t pa = (e & 1) ? (ushort_t)(ua >> 16) : (ushort_t)(ua & 0xffffu);
                ushort_t pb = (e & 1) ? (ushort_t)(ub >> 16) : (ushort_t)(ub & 0xffffu);
                ushort_t qa = (e & 1) ? (ushort_t)(va >> 16) : (ushort_t)(va & 0xffffu);
                ushort_t qb = (e & 1) ? (ushort_t)(vb >> 16) : (ushort_t)(vb & 0xffffu);
                float w0 = __shfl(ex0, hd[j][e], 64);
                float w1 = __shfl(ex1, hd[j][e], 64);
                acc[j][e] += w0 * (bf2f(pa) + bf2f(pb)) + w1 * (bf2f(qa) + bf2f(qb));
            }
        }
        if (lane < 29) {
            int m = lane + 256;
            uint2 a0 = *(const uint2*)(hh0 + 4 * m), b0 = *(const uint2*)(hl0 + 4 * m);
            uint2 a1 = *(const uint2*)(hh1 + 4 * m), b1 = *(const uint2*)(hl1 + 4 * m);
#pragma unroll
            for (int e = 0; e < 4; ++e) {
                unsigned ua = (e < 2) ? a0.x : a0.y, ub = (e < 2) ? b0.x : b0.y;
                unsigned va = (e < 2) ? a1.x : a1.y, vb = (e < 2) ? b1.x : b1.y;
                ushort_t pa = (e & 1) ? (ushort_t)(ua >> 16) : (ushort_t)(ua & 0xffffu);
                ushort_t pb = (e & 1) ? (ushort_t)(ub >> 16) : (ushort_t)(ub & 0xffffu);
                ushort_t qa = (e & 1) ? (ushort_t)(va >> 16) : (ushort_t)(va & 0xffffu);
                ushort_t qb = (e & 1) ? (ushort_t)(vb >> 16) : (ushort_t)(vb & 0xffffu);
                float w0 = __shfl(ex0, hd[4][e], 64);
                float w1 = __shfl(ex1, hd[4][e], 64);
                acc[4][e] += w0 * (bf2f(pa) + bf2f(pb)) + w1 * (bf2f(qa) + bf2f(qb));
            }
        }
    }
    for (; eg < end; ++eg) {
        int s = csr[eg];
        float ex = 0.f;
        if (lane < HH) {
            float t = as_[s * HH + lane] + my_ad;
            t = (t >= 0.f) ? t : 0.2f * t;
            ex = __expf(t);
            den += ex;
        }
        const ushort_t* hh = h0hi + (size_t)s * KP;
        const ushort_t* hl = h0lo + (size_t)s * KP;
#pragma unroll
        for (int j = 0; j < 4; ++j) {
            int m = lane + 64 * j;
            uint2 vh = *(const uint2*)(hh + 4 * m);
            uint2 vl = *(const uint2*)(hl + 4 * m);
#pragma unroll
            for (int e = 0; e < 4; ++e) {
                unsigned ua = (e < 2) ? vh.x : vh.y, ub = (e < 2) ? vl.x : vl.y;
                ushort_t pa = (e & 1) ? (ushort_t)(ua >> 16) : (ushort_t)(ua & 0xffffu);
                ushort_t pb = (e & 1) ? (ushort_t)(ub >> 16) : (ushort_t)(ub & 0xffffu);
                float w0 = __shfl(ex, hd[j][e], 64);
                acc[j][e] += w0 * (bf2f(pa) + bf2f(pb));
            }
        }
        if (lane < 29) {
            int m = lane + 256;
            uint2 vh = *(const uint2*)(hh + 4 * m);
            uint2 vl = *(const uint2*)(hl + 4 * m);
#pragma unroll
            for (int e = 0; e < 4; ++e) {
                unsigned ua = (e < 2) ? vh.x : vh.y, ub = (e < 2) ? vl.x : vl.y;
                ushort_t pa = (e & 1) ? (ushort_t)(ua >> 16) : (ushort_t)(ua & 0xffffu);
                ushort_t pb = (e & 1) ? (ushort_t)(ub >> 16) : (ushort_t)(ub & 0xffffu);
                float w0 = __shfl(ex, hd[4][e], 64);
                acc[4][e] += w0 * (bf2f(pa) + bf2f(pb));
            }
        }
    }

#pragma unroll
    for (int j = 0; j < 5; ++j) {
        int m = lane + 64 * j;
        if (j == 4 && lane >= 32) break;
        unsigned ohx = 0, ohy = 0, olx = 0, oly = 0;
        if (j < 4 || lane < 29) {
            float vv[4];
#pragma unroll
            for (int e = 0; e < 4; ++e) {
                int k = 4 * m + e;
                float d = __shfl(den, hd[j][e], 64);
                float v = acc[j][e] / d + bias[k];
                vv[e] = (v >= 0.f) ? v : 0.01f * v;
            }
            ushort_t h0s = f2bf(vv[0]); ushort_t l0 = f2bf(vv[0] - bf2f(h0s));
            ushort_t h1s = f2bf(vv[1]); ushort_t l1 = f2bf(vv[1] - bf2f(h1s));
            ushort_t h2s = f2bf(vv[2]); ushort_t l2 = f2bf(vv[2] - bf2f(h2s));
            ushort_t h3s = f2bf(vv[3]); ushort_t l3 = f2bf(vv[3] - bf2f(h3s));
            ohx = (unsigned)h0s | ((unsigned)h1s << 16);
            ohy = (unsigned)h2s | ((unsigned)h3s << 16);
            olx = (unsigned)l0 | ((unsigned)l1 << 16);
            oly = (unsigned)l2 | ((unsigned)l3 << 16);
        }
        *(uint2*)(outhi + (size_t)n * KP + 4 * m) = make_uint2(ohx, ohy);
        *(uint2*)(outlo + (size_t)n * KP + 4 * m) = make_uint2(olx, oly);
    }
}

// ---------------- GCN aggregation: one wave per dst node, 2-edge unrolled ----------------

__global__ __launch_bounds__(256) void gcn_agg(
    const float* __restrict__ h2, const int* __restrict__ offs, const int* __restrict__ csr,
    const float* __restrict__ dinv, const float* __restrict__ bias, float* __restrict__ out) {
    int lane = threadIdx.x & 63;
    int n = blockIdx.x * 4 + (threadIdx.x >> 6);
    if (n >= NN) return;
    int beg = offs[n], end = offs[n + 1];
    float di = dinv[n];
    float4 acc[5];
#pragma unroll
    for (int j = 0; j < 5; ++j) acc[j] = make_float4(0.f, 0.f, 0.f, 0.f);

    int eg = beg;
    for (; eg + 2 <= end; eg += 2) {
        int s0 = csr[eg], s1 = csr[eg + 1];
        float w0 = dinv[s0] * di, w1 = dinv[s1] * di;
        const float* r0 = h2 + (size_t)s0 * HFD;
        const float* r1 = h2 + (size_t)s1 * HFD;
#pragma unroll
        for (int j = 0; j < 4; ++j) {
            float4 v0 = *(const float4*)(r0 + 4 * (lane + 64 * j));
            float4 v1 = *(const float4*)(r1 + 4 * (lane + 64 * j));
            acc[j].x += w0 * v0.x + w1 * v1.x;
            acc[j].y += w0 * v0.y + w1 * v1.y;
            acc[j].z += w0 * v0.z + w1 * v1.z;
            acc[j].w += w0 * v0.w + w1 * v1.w;
        }
        if (lane < 29) {
            float4 v0 = *(const float4*)(r0 + 4 * (lane + 256));
            float4 v1 = *(const float4*)(r1 + 4 * (lane + 256));
            acc[4].x += w0 * v0.x + w1 * v1.x;
            acc[4].y += w0 * v0.y + w1 * v1.y;
            acc[4].z += w0 * v0.z + w1 * v1.z;
            acc[4].w += w0 * v0.w + w1 * v1.w;
        }
    }
    for (; eg < end; ++eg) {
        int s = csr[eg];
        float w = dinv[s] * di;
        const float* hrow = h2 + (size_t)s * HFD;
#pragma unroll
        for (int j = 0; j < 4; ++j) {
            float4 v = *(const float4*)(hrow + 4 * (lane + 64 * j));
            acc[j].x += w * v.x; acc[j].y += w * v.y;
            acc[j].z += w * v.z; acc[j].w += w * v.w;
        }
        if (lane < 29) {
            float4 v = *(const float4*)(hrow + 4 * (lane + 256));
            acc[4].x += w * v.x; acc[4].y += w * v.y;
            acc[4].z += w * v.z; acc[4].w += w * v.w;
        }
    }

#pragma unroll
    for (int j = 0; j < 5; ++j) {
        if (j == 4 && lane >= 29) break;
        int m = lane + 64 * j;
        float4 b4 = *(const float4*)(bias + 4 * m);
        float4 o;
        o.x = acc[j].x + b4.x; o.x = (o.x >= 0.f) ? o.x : 0.01f * o.x;
        o.y = acc[j].y + b4.y; o.y = (o.y >= 0.f) ? o.y : 0.01f * o.y;
        o.z = acc[j].z + b4.z; o.z = (o.z >= 0.f) ? o.z : 0.01f * o.z;
        o.w = acc[j].w + b4.w; o.w = (o.w >= 0.f) ? o.w : 0.01f * o.w;
        *(float4*)(out + (size_t)n * HFD + 4 * m) = o;
    }
}

// ---------------- graph pooling (max + mean), float4 ----------------

__global__ void k_pool(const float* __restrict__ hfeat, const int* __restrict__ gs,
                       const int* __restrict__ ge, float* __restrict__ gout) {
    int g = blockIdx.x;
    if (threadIdx.x >= 57) return;
    int m = blockIdx.y * 57 + threadIdx.x;
    int s = gs[g], e = ge[g];
    int cnt = e - s;
    float4 mx = make_float4(-1e30f, -1e30f, -1e30f, -1e30f);
    float4 sm = make_float4(0.f, 0.f, 0.f, 0.f);
    for (int r = s; r < e; ++r) {
        float4 v = *(const float4*)(hfeat + (size_t)r * HFD + 4 * m);
        mx.x = fmaxf(mx.x, v.x); mx.y = fmaxf(mx.y, v.y);
        mx.z = fmaxf(mx.z, v.z); mx.w = fmaxf(mx.w, v.w);
        sm.x += v.x; sm.y += v.y; sm.z += v.z; sm.w += v.w;
    }
    float4 mean;
    if (cnt <= 0) {
        mx = make_float4(0.f, 0.f, 0.f, 0.f);
        mean = make_float4(0.f, 0.f, 0.f, 0.f);
    } else {
        float inv = 1.f / (float)cnt;
        mean = make_float4(sm.x * inv, sm.y * inv, sm.z * inv, sm.w * inv);
    }
    *(float4*)(gout + (size_t)g * (2 * HFD) + 4 * m) = mx;
    *(float4*)(gout + (size_t)g * (2 * HFD) + HFD + 4 * m) = mean;
}

// ---------------- fcg1 split-K (kt loop MUST stay rolled — round-3 spill regression) ----------------

__global__ __launch_bounds__(256) void k_fcg1_part(
    const float* __restrict__ A, const float* __restrict__ B, float* __restrict__ part) {
    __shared__ float As[16][64 + 4];
    __shared__ float Bs[16][64 + 4];
    int tid = threadIdx.x;
    int tx = tid & 15, ty = tid >> 4;
    int row0 = blockIdx.y * 64, col0 = blockIdx.x * 64;
    int kbeg = blockIdx.z * F1KC;
    float acc[4][4] = {};
#pragma unroll 1
    for (int kt = 0; kt < F1KC / 16; ++kt) {
        int kk = kbeg + kt * 16;
#pragma unroll
        for (int l = 0; l < 4; ++l) {
            int idx = tid + 256 * l;
            int m = idx >> 4, k = idx & 15;
            int gr = row0 + m, gk = kk + k;
            As[k][m] = (gk < F1K) ? A[(size_t)gr * F1K + gk] : 0.f;
        }
#pragma unroll
        for (int l = 0; l < 4; ++l) {
            int idx = tid + 256 * l;
            int nn = idx & 63, k = idx >> 6;
            int gc = col0 + nn, gk = kk + k;
            Bs[k][nn] = (gc < 1000 && gk < F1K) ? B[(size_t)gk * 1000 + gc] : 0.f;
        }
        __syncthreads();
#pragma unroll
        for (int k = 0; k < 16; ++k) {
            float4 av = *(const float4*)&As[k][ty * 4];
            float4 bv = *(const float4*)&Bs[k][tx * 4];
            float a[4] = {av.x, av.y, av.z, av.w};
            float b[4] = {bv.x, bv.y, bv.z, bv.w};
#pragma unroll
            for (int i = 0; i < 4; ++i)
#pragma unroll
                for (int j = 0; j < 4; ++j) acc[i][j] += a[i] * b[j];
        }
        __syncthreads();
    }
    float* pc = part + (size_t)blockIdx.z * GG * 1000;
#pragma unroll
    for (int i = 0; i < 4; ++i) {
        int r = row0 + ty * 4 + i;
#pragma unroll
        for (int j = 0; j < 4; ++j) {
            int c = col0 + tx * 4 + j;
            if (c < 1000) pc[(size_t)r * 1000 + c] = acc[i][j];
        }
    }
}

__global__ void k_fcg1_red(const float* __restrict__ part, const float* __restrict__ bias,
                           float* __restrict__ out) {
    int idx = blockIdx.x * 256 + threadIdx.x;
    if (idx >= GG * 1000) return;
    float s = 0.f;
#pragma unroll
    for (int k = 0; k < F1KS; ++k) s += part[(size_t)k * GG * 1000 + idx];
    int n = idx % 1000;
    float v = s + bias[n];
    out[idx] = (v >= 0.f) ? v : 0.01f * v;
}

// ---------------- fcg2 ----------------

__global__ __launch_bounds__(256) void k_fcg2(const float* __restrict__ in, const float* __restrict__ W,
                                              const float* __restrict__ b, float* __restrict__ out) {
    __shared__ float part[4][64];
    int g = blockIdx.x;
    int o = threadIdx.x & 63, p = threadIdx.x >> 6;
    const float* row = in + (size_t)g * 1000;
    float acc = 0.f;
    for (int k = p * 250; k < (p + 1) * 250; ++k) acc += row[k] * W[k * 64 + o];
    part[p][o] = acc;
    __syncthreads();
    if (p == 0) out[(size_t)g * 64 + o] = part[0][o] + part[1][o] + part[2][o] + part[3][o] + b[o];
}

// ---------------- final head ----------------

__global__ __launch_bounds__(256) void k_final(
    const float* __restrict__ b1, const float* __restrict__ b2, const float* __restrict__ target,
    const float* __restrict__ fcxtW, const float* __restrict__ fcxtb,
    const float* __restrict__ fc1W, const float* __restrict__ fc1b,
    const float* __restrict__ fc2W, const float* __restrict__ fc2b,
    const float* __restrict__ outW, const float* __restrict__ outb,
    float* __restrict__ out) {
    __shared__ float xc[256];
    __shared__ float xt2[128];
    __shared__ float y1[128];
    __shared__ float y2[32];
    int g = blockIdx.x, t = threadIdx.x;
    if (t < 64) xc[t] = b1[(size_t)g * 64 + t];
    else if (t < 128) xc[t] = b2[(size_t)g * 64 + (t - 64)];
    {
        int c = t & 127, p = t >> 7;
        float acc = 0.f;
        const float* trow = target + (size_t)g * 1000;
        for (int k = p * 500; k < (p + 1) * 500; ++k) acc += trow[k] * fcxtW[k * 128 + c];
        if (p == 1) xt2[c] = acc;
        __syncthreads();
        if (p == 0) xc[128 + c] = acc + xt2[c] + fcxtb[c];
    }
    __syncthreads();
    if (t < 128) {
        float acc = 0.f;
        for (int k = 0; k < 256; ++k) acc += xc[k] * fc1W[k * 128 + t];
        acc += fc1b[t];
        y1[t] = (acc >= 0.f) ? acc : 0.01f * acc;
    }
    __syncthreads();
    if (t < 32) {
        float acc = 0.f;
        for (int k = 0; k < 128; ++k) acc += y1[k] * fc2W[k * 32 + t];
        acc += fc2b[t];
        y2[t] = (acc >= 0.f) ? acc : 0.01f * acc;
    }
    __syncthreads();
    if (t == 0) {
        float acc = 0.f;
        for (int k = 0; k < 32; ++k) acc += y2[k] * outW[k];
        out[g] = acc + outb[0];
    }
}

// ---------------- host launch ----------------

extern "C" void kernel_launch(void* const* d_in, const int* in_sizes, int n_in,
                              void* d_out, int out_size, void* d_ws, size_t ws_size,
                              hipStream_t stream) {
    (void)in_sizes; (void)n_in; (void)out_size; (void)ws_size;

    size_t off = 0;
    auto alloc = [&](size_t bytes) -> void* {
        void* p = (char*)d_ws + off;
        off += (bytes + 255) & ~(size_t)255;
        return p;
    };
    char* regionA = (char*)alloc((size_t)2 * NN * KP * 2);
    char* regionB = (char*)alloc((size_t)2 * NN * KP * 2);
    ushort_t* Bthi = (ushort_t*)alloc((size_t)KP * KP * 2);
    ushort_t* Btlo = (ushort_t*)alloc((size_t)KP * KP * 2);
    float* a_s    = (float*)alloc((size_t)NN * HH * 4);
    float* a_d    = (float*)alloc((size_t)NN * HH * 4);
    int*   deg    = (int*)alloc((size_t)NN * 4);
    int*   offs   = (int*)alloc((size_t)(NN + 1) * 4);
    int*   cursor = (int*)alloc((size_t)NN * 4);
    int*   csr    = (int*)alloc((size_t)EPRIME * 4);
    float* dinv   = (float*)alloc((size_t)NN * 4);
    int*   gstart = (int*)alloc((size_t)GG * 4);
    int*   gend   = (int*)alloc((size_t)GG * 4);
    int*   bsum   = (int*)alloc((size_t)128 * 4);
    float* gpool  = (float*)alloc((size_t)GG * 2 * HFD * 4);
    float* fc1out = (float*)alloc((size_t)GG * 1000 * 4);
    float* bout   = (float*)alloc((size_t)2 * GG * 64 * 4);

    // overlays
    ushort_t* h0hi = (ushort_t*)regionA;
    ushort_t* h0lo = (ushort_t*)regionA + (size_t)NN * KP;
    float*    h2f  = (float*)regionA;                        // after h0 is dead
    float*    f1part = (float*)regionA;                      // after h2 is dead
    ushort_t* xhi  = (ushort_t*)regionB;
    ushort_t* xlo  = (ushort_t*)regionB + (size_t)NN * 128;
    ushort_t* h1hi = (ushort_t*)regionB;                     // after x is dead
    ushort_t* h1lo = (ushort_t*)regionB + (size_t)NN * KP;
    float*    hgcn = (float*)regionB;                        // after h1 is dead

    const float* target = (const float*)d_in[6];
    const int NRB = cdiv(NN, 128);        // 157 row blocks
    const int NCB = KP / 128;             // 9 col blocks

    for (int b = 0; b < 2; ++b) {
        const float* x     = (const float*)d_in[b ? 3 : 0];
        const int*   ei    = (const int*)d_in[b ? 4 : 1];
        const int*   batch = (const int*)d_in[b ? 5 : 2];
        int pb = 7 + b * 10;
        const float* gatW    = (const float*)d_in[pb + 0];
        const float* att_src = (const float*)d_in[pb + 1];
        const float* att_dst = (const float*)d_in[pb + 2];
        const float* gatb    = (const float*)d_in[pb + 3];
        const float* gcnW    = (const float*)d_in[pb + 4];
        const float* gcnb    = (const float*)d_in[pb + 5];
        const float* f1W     = (const float*)d_in[pb + 6];
        const float* f1b     = (const float*)d_in[pb + 7];
        const float* f2W     = (const float*)d_in[pb + 8];
        const float* f2b     = (const float*)d_in[pb + 9];

        // CSR
        hipLaunchKernelGGL(k_init, dim3(cdiv(NN, 256)), dim3(256), 0, stream, deg, gstart, gend);
        hipLaunchKernelGGL(k_count, dim3(cdiv(EE, 256)), dim3(256), 0, stream, ei, deg);
        hipLaunchKernelGGL(k_scan1, dim3(NSCB), dim3(256), 0, stream, deg, offs, bsum);
        hipLaunchKernelGGL(k_scan2, dim3(1), dim3(128), 0, stream, bsum);
        hipLaunchKernelGGL(k_scan3prep, dim3(NSCB), dim3(256), 0, stream,
                           offs, bsum, cursor, deg, dinv, batch, gstart, gend);
        hipLaunchKernelGGL(k_fill, dim3(cdiv(EPRIME, 256)), dim3(256), 0, stream, ei, cursor, csr);

        // x -> split (regionB), gatW -> transpose split
        hipLaunchKernelGGL(k_split_x, dim3(cdiv(NN * 128, 256)), dim3(256), 0, stream, x, xhi, xlo);
        hipLaunchKernelGGL(k_tsplitT, dim3(128 / 64, KP / 64), dim3(256), 0, stream,
                           gatW, FF, HFD, 128, Bthi, Btlo);

        // h0 = x @ gatW -> split pair (regionA). ksteps=4 (Kpad=128)
        hipLaunchKernelGGL((mfma_gemm<1>), dim3(NRB * NCB), dim3(256), 0, stream,
                           xhi, xlo, Bthi, Btlo, 128, 128, NN, HFD, 4, NCB,
                           (float*)nullptr, 0, h0hi, h0lo, KP);

        // attention logits
        hipLaunchKernelGGL(k_att, dim3(cdiv(NN * HH, 256)), dim3(256), 0, stream,
                           h0hi, h0lo, att_src, att_dst, a_s, a_d);

        // GAT aggregate -> h1 split (regionB)
        hipLaunchKernelGGL(gat_agg, dim3(cdiv(NN, 4)), dim3(256), 0, stream,
                           h0hi, h0lo, a_s, a_d, offs, csr, gatb, h1hi, h1lo);

        // gcnW -> transpose split
        hipLaunchKernelGGL(k_tsplitT, dim3(KP / 64, KP / 64), dim3(256), 0, stream,
                           gcnW, HFD, HFD, KP, Bthi, Btlo);

        // h2 = h1 @ gcnW -> fp32 (regionA). ksteps=36
        hipLaunchKernelGGL((mfma_gemm<0>), dim3(NRB * NCB), dim3(256), 0, stream,
                           h1hi, h1lo, Bthi, Btlo, KP, KP, NN, HFD, KP / 32, NCB,
                           h2f, HFD, (ushort_t*)nullptr, (ushort_t*)nullptr, 0);

        // GCN aggregate -> hgcn (regionB)
        hipLaunchKernelGGL(gcn_agg, dim3(cdiv(NN, 4)), dim3(256), 0, stream,
                           h2f, offs, csr, dinv, gcnb, hgcn);

        // pooling
        hipLaunchKernelGGL(k_pool, dim3(GG, 5), dim3(64), 0, stream, hgcn, gstart, gend, gpool);

        // fcg1 split-K
        hipLaunchKernelGGL(k_fcg1_part, dim3(16, 2, F1KS), dim3(256), 0, stream,
                           gpool, f1W, f1part);
        hipLaunchKernelGGL(k_fcg1_red, dim3(cdiv(GG * 1000, 256)), dim3(256), 0, stream,
                           f1part, f1b, fc1out);

        // fcg2
        hipLaunchKernelGGL(k_fcg2, dim3(GG), dim3(256), 0, stream,
                           fc1out, f2W, f2b, bout + (size_t)b * GG * 64);
    }

    hipLaunchKernelGGL(k_final, dim3(GG), dim3(256), 0, stream,
                       bout, bout + (size_t)GG * 64, target,
                       (const float*)d_in[27], (const float*)d_in[28],
                       (const float*)d_in[29], (const float*)d_in[30],
                       (const float*)d_in[31], (const float*)d_in[32],
                       (const float*)d_in[33], (const float*)d_in[34],
                       (float*)d_out);
}

// Round 8
// 1573.260 us; speedup vs baseline: 1.1788x; 1.1788x over previous
//
#include <hip/hip_runtime.h>
#include <cstddef>
#include <cstdint>

#define NN 20000
#define EE 160000
#define EPRIME 180000   // EE + NN (self loops)
#define GG 128
#define FF 114
#define HH 10
#define HFD 1140        // FF*HH
#define KP 1152         // padded feature dim (36*32, 9*128)
#define F1K 2280        // fcg1 K
#define F1KS 18         // split-K chunks
#define F1KC 128        // chunk size
#define NSCB 79         // scan blocks = cdiv(NN,256)

typedef unsigned short ushort_t;
typedef __attribute__((ext_vector_type(8))) short bf16x8;
typedef __attribute__((ext_vector_type(4))) float f32x4;

static inline int cdiv(int a, int b) { return (a + b - 1) / b; }

// ---------------- bf16 helpers ----------------

__device__ __forceinline__ ushort_t f2bf(float v) {
    union { float f; unsigned u; } c; c.f = v;
    unsigned u = c.u;
    unsigned r = (u + 0x7fffu + ((u >> 16) & 1u)) >> 16;   // RNE
    return (ushort_t)r;
}
__device__ __forceinline__ float bf2f(ushort_t h) {
    union { unsigned u; float f; } c; c.u = ((unsigned)h) << 16;
    return c.f;
}
// unpack packed (hi | lo<<16) u32 -> fp32 value
__device__ __forceinline__ float pk2f(unsigned w) {
    return bf2f((ushort_t)(w & 0xffffu)) + bf2f((ushort_t)(w >> 16));
}

__device__ __forceinline__ void gload16(const void* g, const ushort_t* l) {
    __builtin_amdgcn_global_load_lds(
        (const __attribute__((address_space(1))) unsigned int*)g,
        (__attribute__((address_space(3))) unsigned int*)l, 16, 0, 0);
}

// ---------------- CSR construction ----------------

__global__ void k_init(int* __restrict__ deg, int* __restrict__ gstart, int* __restrict__ gend) {
    int i = blockIdx.x * blockDim.x + threadIdx.x;
    if (i < NN) deg[i] = 1;               // self loop
    if (i < GG) { gstart[i] = NN; gend[i] = 0; }
}

__global__ void k_count(const int* __restrict__ ei, int* __restrict__ deg) {
    int i = blockIdx.x * blockDim.x + threadIdx.x;
    if (i < EE) atomicAdd(&deg[ei[EE + i]], 1);
}

// hierarchical scan: per-block inclusive + block totals
__global__ void k_scan1(const int* __restrict__ deg, int* __restrict__ offs, int* __restrict__ bsum) {
    __shared__ int tmp[256];
    int b = blockIdx.x, tid = threadIdx.x;
    int i = b * 256 + tid;
    int v = (i < NN) ? deg[i] : 0;
    tmp[tid] = v;
    __syncthreads();
#pragma unroll
    for (int off = 1; off < 256; off <<= 1) {
        int t = (tid >= off) ? tmp[tid - off] : 0;
        __syncthreads();
        tmp[tid] += t;
        __syncthreads();
    }
    if (i < NN) offs[i + 1] = tmp[tid];
    if (tid == 255) bsum[b] = tmp[255];
}

__global__ void k_scan2(int* __restrict__ bsum) {
    __shared__ int tmp[128];
    int tid = threadIdx.x;
    int v = (tid < NSCB) ? bsum[tid] : 0;
    tmp[tid] = v;
    __syncthreads();
#pragma unroll
    for (int off = 1; off < 128; off <<= 1) {
        int t = (tid >= off) ? tmp[tid - off] : 0;
        __syncthreads();
        tmp[tid] += t;
        __syncthreads();
    }
    if (tid < NSCB) bsum[tid] = tmp[tid] - v;   // exclusive prefix
}

// fused: finalize offs + cursor + dinv + graph ranges
__global__ void k_scan3prep(int* __restrict__ offs, const int* __restrict__ bsum,
                            int* __restrict__ cursor, const int* __restrict__ deg,
                            float* __restrict__ dinv, const int* __restrict__ batch,
                            int* __restrict__ gstart, int* __restrict__ gend) {
    int i = blockIdx.x * 256 + threadIdx.x;
    if (i < NN) {
        int o = offs[i + 1] + bsum[i >> 8];   // inclusive prefix up to i
        offs[i + 1] = o;
        cursor[i] = o - deg[i];               // exclusive prefix = offs[i]
        dinv[i] = rsqrtf((float)deg[i]);
        int b = batch[i];
        atomicMin(&gstart[b], i);
        atomicMax(&gend[b], i + 1);
    }
    if (i == 0) offs[0] = 0;
}

__global__ void k_fill(const int* __restrict__ ei, int* __restrict__ cursor, int* __restrict__ csr) {
    int i = blockIdx.x * blockDim.x + threadIdx.x;
    if (i < EPRIME) {
        int s, d;
        if (i < EE) { s = ei[i]; d = ei[EE + i]; }
        else        { s = i - EE; d = s; }
        int pos = atomicAdd(&cursor[d], 1);
        csr[pos] = s;
    }
}

// ---------------- split / transpose-split conversions ----------------

__global__ void k_split_x(const float* __restrict__ x, ushort_t* __restrict__ xhi, ushort_t* __restrict__ xlo) {
    int idx = blockIdx.x * 256 + threadIdx.x;
    if (idx >= NN * 128) return;
    int n = idx >> 7, k = idx & 127;
    float v = (k < FF) ? x[(size_t)n * FF + k] : 0.f;
    ushort_t hi = f2bf(v);
    ushort_t lo = f2bf(v - bf2f(hi));
    xhi[idx] = hi; xlo[idx] = lo;
}

// W [K,Nc] -> T[n][k]=W[k][n], split bf16, zero pad. Coalesced via LDS 64x64 tiles.
__global__ __launch_bounds__(256) void k_tsplitT(const float* __restrict__ W, int K, int Nc,
                                                 int Kpad, ushort_t* __restrict__ Thi,
                                                 ushort_t* __restrict__ Tlo) {
    __shared__ float tile[64][65];
    int kb = blockIdx.x * 64;
    int nb = blockIdx.y * 64;
    int c = threadIdx.x & 63, r4 = threadIdx.x >> 6;
#pragma unroll
    for (int rr = 0; rr < 16; ++rr) {
        int r = r4 * 16 + rr;
        int gk = kb + r, gn = nb + c;
        tile[r][c] = (gk < K && gn < Nc) ? W[(size_t)gk * Nc + gn] : 0.f;
    }
    __syncthreads();
#pragma unroll
    for (int rr = 0; rr < 16; ++rr) {
        int r = r4 * 16 + rr;
        int gn = nb + r, gk = kb + c;
        float v = tile[c][r];
        ushort_t hi = f2bf(v);
        ushort_t lo = f2bf(v - bf2f(hi));
        size_t o = (size_t)gn * Kpad + gk;
        Thi[o] = hi; Tlo[o] = lo;
    }
}

// ---------------- split-bf16 MFMA GEMM, 2-phase double-buffered + XCD swizzle ----------------
// (round-5 structure: best measured 252us. r6 3-stage and r7 B-direct both regressed.)
// OUTMODE 0: fp32 C. OUTMODE 1: packed u32 (hi | lo<<16) Cpk (for gather consumers).

template <int OUTMODE>
__global__ __launch_bounds__(256) void mfma_gemm(
    const ushort_t* __restrict__ Ahi, const ushort_t* __restrict__ Alo,
    const ushort_t* __restrict__ Bthi, const ushort_t* __restrict__ Btlo,
    int lda, int ldb, int M, int Nreal, int ksteps, int ncb,
    float* __restrict__ C, int ldc,
    unsigned* __restrict__ Cpk, int ldcs) {
    __shared__ __align__(16) ushort_t lds[2 * 4 * 4096];   // [buf][plane][4 kg][128 row][8]
    const int tid = threadIdx.x;
    const int lane = tid & 63;
    const int w = tid >> 6;
    const int wr = w >> 1, wc = w & 1;

    // bijective XCD-chunked swizzle (m204)
    int nwg = gridDim.x;
    int q = nwg >> 3, r8 = nwg & 7;
    int xcd = blockIdx.x & 7, sidx = blockIdx.x >> 3;
    int wg = (xcd < r8 ? xcd * (q + 1) : r8 * (q + 1) + (xcd - r8) * q) + sidx;
    int brow = wg / ncb, bcol = wg - brow * ncb;

    int row0 = brow * 128; if (row0 > M - 128) row0 = M - 128;   // overlap trick, idempotent writes
    const int col0 = bcol * 128;

    f32x4 acc[4][4];
#pragma unroll
    for (int i = 0; i < 4; ++i)
#pragma unroll
        for (int j = 0; j < 4; ++j) acc[i][j] = (f32x4){0.f, 0.f, 0.f, 0.f};

    const size_t ldaB = (size_t)lda * 2, ldbB = (size_t)ldb * 2;
    const char* pAhi[2]; const char* pAlo[2]; const char* pBhi[2]; const char* pBlo[2];
    unsigned ldsoff[2];
#pragma unroll
    for (int i = 0; i < 2; ++i) {
        int c = (w * 2 + i) * 64 + lane;
        int kg = c >> 7, r = c & 127;
        pAhi[i] = (const char*)Ahi + (size_t)(row0 + r) * ldaB + kg * 16;
        pAlo[i] = (const char*)Alo + (size_t)(row0 + r) * ldaB + kg * 16;
        pBhi[i] = (const char*)Bthi + (size_t)(col0 + r) * ldbB + kg * 16;
        pBlo[i] = (const char*)Btlo + (size_t)(col0 + r) * ldbB + kg * 16;
        ldsoff[i] = (w * 2 + i) * 512;
    }
    const int kgf = lane >> 4, r15 = lane & 15;

    auto STAGE = [&](int buf, int ks) {
        size_t kb = (size_t)ks * 64;
        unsigned bo = buf ? 16384u : 0u;
#pragma unroll
        for (int i = 0; i < 2; ++i) {
            gload16(pAhi[i] + kb, lds + bo + 0 * 4096 + ldsoff[i]);
            gload16(pAlo[i] + kb, lds + bo + 1 * 4096 + ldsoff[i]);
            gload16(pBhi[i] + kb, lds + bo + 2 * 4096 + ldsoff[i]);
            gload16(pBlo[i] + kb, lds + bo + 3 * 4096 + ldsoff[i]);
        }
    };

    STAGE(0, 0);
    asm volatile("s_waitcnt vmcnt(0)" ::: "memory");
    __syncthreads();
    int cur = 0;

    for (int ks = 0; ks < ksteps; ++ks) {
        if (ks + 1 < ksteps) STAGE(cur ^ 1, ks + 1);   // prefetch flies during MFMA
        const ushort_t* lb = lds + (cur ? 16384u : 0u);
        bf16x8 ah[4], al[4], bh[4], bl[4];
#pragma unroll
        for (int i = 0; i < 4; ++i) {
            int ra = wr * 64 + i * 16 + r15;
            int rb = wc * 64 + i * 16 + r15;
            ah[i] = *(const bf16x8*)(lb + 0 * 4096 + kgf * 1024 + ra * 8);
            al[i] = *(const bf16x8*)(lb + 1 * 4096 + kgf * 1024 + ra * 8);
            bh[i] = *(const bf16x8*)(lb + 2 * 4096 + kgf * 1024 + rb * 8);
            bl[i] = *(const bf16x8*)(lb + 3 * 4096 + kgf * 1024 + rb * 8);
        }
#pragma unroll
        for (int i = 0; i < 4; ++i)
#pragma unroll
            for (int j = 0; j < 4; ++j) {
                acc[i][j] = __builtin_amdgcn_mfma_f32_16x16x32_bf16(ah[i], bh[j], acc[i][j], 0, 0, 0);
                acc[i][j] = __builtin_amdgcn_mfma_f32_16x16x32_bf16(ah[i], bl[j], acc[i][j], 0, 0, 0);
                acc[i][j] = __builtin_amdgcn_mfma_f32_16x16x32_bf16(al[i], bh[j], acc[i][j], 0, 0, 0);
            }
        asm volatile("s_waitcnt vmcnt(0)" ::: "memory");
        __syncthreads();
        cur ^= 1;
    }

    const int g4 = lane >> 4;
#pragma unroll
    for (int i = 0; i < 4; ++i)
#pragma unroll
        for (int j = 0; j < 4; ++j) {
            int c = col0 + wc * 64 + j * 16 + r15;
#pragma unroll
            for (int reg = 0; reg < 4; ++reg) {
                int r = row0 + wr * 64 + i * 16 + g4 * 4 + reg;
                float v = acc[i][j][reg];
                if (OUTMODE == 0) {
                    if (r < M && c < Nreal) C[(size_t)r * ldc + c] = v;
                } else {
                    if (r < M) {
                        if (c >= Nreal) v = 0.f;
                        ushort_t hi = f2bf(v);
                        ushort_t lo = f2bf(v - bf2f(hi));
                        Cpk[(size_t)r * ldcs + c] = (unsigned)hi | ((unsigned)lo << 16);
                    }
                }
            }
        }
}

// ---------------- attention logits from packed h0 ----------------

__global__ void k_att(const unsigned* __restrict__ h0pk,
                      const float* __restrict__ att_src, const float* __restrict__ att_dst,
                      float* __restrict__ as_, float* __restrict__ ad_) {
    int id = blockIdx.x * blockDim.x + threadIdx.x;
    if (id >= NN * HH) return;
    int n = id / HH, h = id % HH;
    const unsigned* row = h0pk + (size_t)n * KP + h * FF;
    const float* ws = att_src + h * FF;
    const float* wd = att_dst + h * FF;
    float as = 0.f, ad = 0.f;
    for (int f = 0; f < FF; f += 2) {
        uint2 q = *(const uint2*)(row + f);
        float v0 = pk2f(q.x);
        float v1 = pk2f(q.y);
        as += v0 * ws[f] + v1 * ws[f + 1];
        ad += v0 * wd[f] + v1 * wd[f + 1];
    }
    as_[id] = as;
    ad_[id] = ad;
}

// ---------------- GAT aggregation: packed h0 input, 2-edge unroll ----------------
// softmax WITHOUT max-subtraction (shift-invariant; logits are O(1))

__global__ __launch_bounds__(256) void gat_agg(
    const unsigned* __restrict__ h0pk,
    const float* __restrict__ as_, const float* __restrict__ ad_,
    const int* __restrict__ offs, const int* __restrict__ csr,
    const float* __restrict__ bias,
    ushort_t* __restrict__ outhi, ushort_t* __restrict__ outlo) {
    int lane = threadIdx.x & 63;
    int n = blockIdx.x * 4 + (threadIdx.x >> 6);
    if (n >= NN) return;
    int beg = offs[n], end = offs[n + 1];
    float my_ad = (lane < HH) ? ad_[n * HH + lane] : 0.f;

    int hd[5][4];
#pragma unroll
    for (int j = 0; j < 5; ++j)
#pragma unroll
        for (int e = 0; e < 4; ++e) {
            int k = 4 * (lane + 64 * j) + e;
            hd[j][e] = (k < HFD) ? (k / FF) : 0;
        }

    float den = 0.f;
    float acc[5][4];
#pragma unroll
    for (int j = 0; j < 5; ++j)
#pragma unroll
        for (int e = 0; e < 4; ++e) acc[j][e] = 0.f;

    int eg = beg;
    for (; eg + 2 <= end; eg += 2) {
        int s0 = csr[eg], s1 = csr[eg + 1];
        float ex0 = 0.f, ex1 = 0.f;
        if (lane < HH) {
            float t0 = as_[s0 * HH + lane] + my_ad; t0 = (t0 >= 0.f) ? t0 : 0.2f * t0;
            float t1 = as_[s1 * HH + lane] + my_ad; t1 = (t1 >= 0.f) ? t1 : 0.2f * t1;
            ex0 = __expf(t0); ex1 = __expf(t1);
            den += ex0 + ex1;
        }
        const unsigned* hp0 = h0pk + (size_t)s0 * KP;
        const unsigned* hp1 = h0pk + (size_t)s1 * KP;
#pragma unroll
        for (int j = 0; j < 4; ++j) {
            int m = lane + 64 * j;
            uint4 q0 = *(const uint4*)(hp0 + 4 * m);
            uint4 q1 = *(const uint4*)(hp1 + 4 * m);
            float w00 = __shfl(ex0, hd[j][0], 64), w10 = __shfl(ex1, hd[j][0], 64);
            float w01 = __shfl(ex0, hd[j][1], 64), w11 = __shfl(ex1, hd[j][1], 64);
            float w02 = __shfl(ex0, hd[j][2], 64), w12 = __shfl(ex1, hd[j][2], 64);
            float w03 = __shfl(ex0, hd[j][3], 64), w13 = __shfl(ex1, hd[j][3], 64);
            acc[j][0] += w00 * pk2f(q0.x) + w10 * pk2f(q1.x);
            acc[j][1] += w01 * pk2f(q0.y) + w11 * pk2f(q1.y);
            acc[j][2] += w02 * pk2f(q0.z) + w12 * pk2f(q1.z);
            acc[j][3] += w03 * pk2f(q0.w) + w13 * pk2f(q1.w);
        }
        if (lane < 29) {
            int m = lane + 256;
            uint4 q0 = *(const uint4*)(hp0 + 4 * m);
            uint4 q1 = *(const uint4*)(hp1 + 4 * m);
            float w00 = __shfl(ex0, hd[4][0], 64), w10 = __shfl(ex1, hd[4][0], 64);
            float w01 = __shfl(ex0, hd[4][1], 64), w11 = __shfl(ex1, hd[4][1], 64);
            float w02 = __shfl(ex0, hd[4][2], 64), w12 = __shfl(ex1, hd[4][2], 64);
            float w03 = __shfl(ex0, hd[4][3], 64), w13 = __shfl(ex1, hd[4][3], 64);
            acc[4][0] += w00 * pk2f(q0.x) + w10 * pk2f(q1.x);
            acc[4][1] += w01 * pk2f(q0.y) + w11 * pk2f(q1.y);
            acc[4][2] += w02 * pk2f(q0.z) + w12 * pk2f(q1.z);
            acc[4][3] += w03 * pk2f(q0.w) + w13 * pk2f(q1.w);
        }
    }
    for (; eg < end; ++eg) {
        int s = csr[eg];
        float ex = 0.f;
        if (lane < HH) {
            float t = as_[s * HH + lane] + my_ad;
            t = (t >= 0.f) ? t : 0.2f * t;
            ex = __expf(t);
            den += ex;
        }
        const unsigned* hp = h0pk + (size_t)s * KP;
#pragma unroll
        for (int j = 0; j < 4; ++j) {
            int m = lane + 64 * j;
            uint4 q = *(const uint4*)(hp + 4 * m);
            acc[j][0] += __shfl(ex, hd[j][0], 64) * pk2f(q.x);
            acc[j][1] += __shfl(ex, hd[j][1], 64) * pk2f(q.y);
            acc[j][2] += __shfl(ex, hd[j][2], 64) * pk2f(q.z);
            acc[j][3] += __shfl(ex, hd[j][3], 64) * pk2f(q.w);
        }
        if (lane < 29) {
            int m = lane + 256;
            uint4 q = *(const uint4*)(hp + 4 * m);
            acc[4][0] += __shfl(ex, hd[4][0], 64) * pk2f(q.x);
            acc[4][1] += __shfl(ex, hd[4][1], 64) * pk2f(q.y);
            acc[4][2] += __shfl(ex, hd[4][2], 64) * pk2f(q.z);
            acc[4][3] += __shfl(ex, hd[4][3], 64) * pk2f(q.w);
        }
    }

#pragma unroll
    for (int j = 0; j < 5; ++j) {
        int m = lane + 64 * j;
        if (j == 4 && lane >= 32) break;
        unsigned ohx = 0, ohy = 0, olx = 0, oly = 0;
        if (j < 4 || lane < 29) {
            float vv[4];
#pragma unroll
            for (int e = 0; e < 4; ++e) {
                int k = 4 * m + e;
                float d = __shfl(den, hd[j][e], 64);
                float v = acc[j][e] / d + bias[k];
                vv[e] = (v >= 0.f) ? v : 0.01f * v;
            }
            ushort_t h0s = f2bf(vv[0]); ushort_t l0 = f2bf(vv[0] - bf2f(h0s));
            ushort_t h1s = f2bf(vv[1]); ushort_t l1 = f2bf(vv[1] - bf2f(h1s));
            ushort_t h2s = f2bf(vv[2]); ushort_t l2 = f2bf(vv[2] - bf2f(h2s));
            ushort_t h3s = f2bf(vv[3]); ushort_t l3 = f2bf(vv[3] - bf2f(h3s));
            ohx = (unsigned)h0s | ((unsigned)h1s << 16);
            ohy = (unsigned)h2s | ((unsigned)h3s << 16);
            olx = (unsigned)l0 | ((unsigned)l1 << 16);
            oly = (unsigned)l2 | ((unsigned)l3 << 16);
        }
        // lanes 29..31 at j=4 write zeros (pad cols 1140..1151 must be 0)
        *(uint2*)(outhi + (size_t)n * KP + 4 * m) = make_uint2(ohx, ohy);
        *(uint2*)(outlo + (size_t)n * KP + 4 * m) = make_uint2(olx, oly);
    }
}

// ---------------- GCN aggregation: one wave per dst node, 2-edge unrolled ----------------

__global__ __launch_bounds__(256) void gcn_agg(
    const float* __restrict__ h2, const int* __restrict__ offs, const int* __restrict__ csr,
    const float* __restrict__ dinv, const float* __restrict__ bias, float* __restrict__ out) {
    int lane = threadIdx.x & 63;
    int n = blockIdx.x * 4 + (threadIdx.x >> 6);
    if (n >= NN) return;
    int beg = offs[n], end = offs[n + 1];
    float di = dinv[n];
    float4 acc[5];
#pragma unroll
    for (int j = 0; j < 5; ++j) acc[j] = make_float4(0.f, 0.f, 0.f, 0.f);

    int eg = beg;
    for (; eg + 2 <= end; eg += 2) {
        int s0 = csr[eg], s1 = csr[eg + 1];
        float w0 = dinv[s0] * di, w1 = dinv[s1] * di;
        const float* r0 = h2 + (size_t)s0 * HFD;
        const float* r1 = h2 + (size_t)s1 * HFD;
#pragma unroll
        for (int j = 0; j < 4; ++j) {
            float4 v0 = *(const float4*)(r0 + 4 * (lane + 64 * j));
            float4 v1 = *(const float4*)(r1 + 4 * (lane + 64 * j));
            acc[j].x += w0 * v0.x + w1 * v1.x;
            acc[j].y += w0 * v0.y + w1 * v1.y;
            acc[j].z += w0 * v0.z + w1 * v1.z;
            acc[j].w += w0 * v0.w + w1 * v1.w;
        }
        if (lane < 29) {
            float4 v0 = *(const float4*)(r0 + 4 * (lane + 256));
            float4 v1 = *(const float4*)(r1 + 4 * (lane + 256));
            acc[4].x += w0 * v0.x + w1 * v1.x;
            acc[4].y += w0 * v0.y + w1 * v1.y;
            acc[4].z += w0 * v0.z + w1 * v1.z;
            acc[4].w += w0 * v0.w + w1 * v1.w;
        }
    }
    for (; eg < end; ++eg) {
        int s = csr[eg];
        float w = dinv[s] * di;
        const float* hrow = h2 + (size_t)s * HFD;
#pragma unroll
        for (int j = 0; j < 4; ++j) {
            float4 v = *(const float4*)(hrow + 4 * (lane + 64 * j));
            acc[j].x += w * v.x; acc[j].y += w * v.y;
            acc[j].z += w * v.z; acc[j].w += w * v.w;
        }
        if (lane < 29) {
            float4 v = *(const float4*)(hrow + 4 * (lane + 256));
            acc[4].x += w * v.x; acc[4].y += w * v.y;
            acc[4].z += w * v.z; acc[4].w += w * v.w;
        }
    }

#pragma unroll
    for (int j = 0; j < 5; ++j) {
        if (j == 4 && lane >= 29) break;
        int m = lane + 64 * j;
        float4 b4 = *(const float4*)(bias + 4 * m);
        float4 o;
        o.x = acc[j].x + b4.x; o.x = (o.x >= 0.f) ? o.x : 0.01f * o.x;
        o.y = acc[j].y + b4.y; o.y = (o.y >= 0.f) ? o.y : 0.01f * o.y;
        o.z = acc[j].z + b4.z; o.z = (o.z >= 0.f) ? o.z : 0.01f * o.z;
        o.w = acc[j].w + b4.w; o.w = (o.w >= 0.f) ? o.w : 0.01f * o.w;
        *(float4*)(out + (size_t)n * HFD + 4 * m) = o;
    }
}

// ---------------- graph pooling (max + mean), float4 ----------------

__global__ void k_pool(const float* __restrict__ hfeat, const int* __restrict__ gs,
                       const int* __restrict__ ge, float* __restrict__ gout) {
    int g = blockIdx.x;
    if (threadIdx.x >= 57) return;
    int m = blockIdx.y * 57 + threadIdx.x;
    int s = gs[g], e = ge[g];
    int cnt = e - s;
    float4 mx = make_float4(-1e30f, -1e30f, -1e30f, -1e30f);
    float4 sm = make_float4(0.f, 0.f, 0.f, 0.f);
    for (int r = s; r < e; ++r) {
        float4 v = *(const float4*)(hfeat + (size_t)r * HFD + 4 * m);
        mx.x = fmaxf(mx.x, v.x); mx.y = fmaxf(mx.y, v.y);
        mx.z = fmaxf(mx.z, v.z); mx.w = fmaxf(mx.w, v.w);
        sm.x += v.x; sm.y += v.y; sm.z += v.z; sm.w += v.w;
    }
    float4 mean;
    if (cnt <= 0) {
        mx = make_float4(0.f, 0.f, 0.f, 0.f);
        mean = make_float4(0.f, 0.f, 0.f, 0.f);
    } else {
        float inv = 1.f / (float)cnt;
        mean = make_float4(sm.x * inv, sm.y * inv, sm.z * inv, sm.w * inv);
    }
    *(float4*)(gout + (size_t)g * (2 * HFD) + 4 * m) = mx;
    *(float4*)(gout + (size_t)g * (2 * HFD) + HFD + 4 * m) = mean;
}

// ---------------- fcg1 split-K (kt loop MUST stay rolled — round-3 spill regression) ----------------

__global__ __launch_bounds__(256) void k_fcg1_part(
    const float* __restrict__ A, const float* __restrict__ B, float* __restrict__ part) {
    __shared__ float As[16][64 + 4];
    __shared__ float Bs[16][64 + 4];
    int tid = threadIdx.x;
    int tx = tid & 15, ty = tid >> 4;
    int row0 = blockIdx.y * 64, col0 = blockIdx.x * 64;
    int kbeg = blockIdx.z * F1KC;
    float acc[4][4] = {};
#pragma unroll 1
    for (int kt = 0; kt < F1KC / 16; ++kt) {
        int kk = kbeg + kt * 16;
#pragma unroll
        for (int l = 0; l < 4; ++l) {
            int idx = tid + 256 * l;
            int m = idx >> 4, k = idx & 15;
            int gr = row0 + m, gk = kk + k;
            As[k][m] = (gk < F1K) ? A[(size_t)gr * F1K + gk] : 0.f;
        }
#pragma unroll
        for (int l = 0; l < 4; ++l) {
            int idx = tid + 256 * l;
            int nn = idx & 63, k = idx >> 6;
            int gc = col0 + nn, gk = kk + k;
            Bs[k][nn] = (gc < 1000 && gk < F1K) ? B[(size_t)gk * 1000 + gc] : 0.f;
        }
        __syncthreads();
#pragma unroll
        for (int k = 0; k < 16; ++k) {
            float4 av = *(const float4*)&As[k][ty * 4];
            float4 bv = *(const float4*)&Bs[k][tx * 4];
            float a[4] = {av.x, av.y, av.z, av.w};
            float b[4] = {bv.x, bv.y, bv.z, bv.w};
#pragma unroll
            for (int i = 0; i < 4; ++i)
#pragma unroll
                for (int j = 0; j < 4; ++j) acc[i][j] += a[i] * b[j];
        }
        __syncthreads();
    }
    float* pc = part + (size_t)blockIdx.z * GG * 1000;
#pragma unroll
    for (int i = 0; i < 4; ++i) {
        int r = row0 + ty * 4 + i;
#pragma unroll
        for (int j = 0; j < 4; ++j) {
            int c = col0 + tx * 4 + j;
            if (c < 1000) pc[(size_t)r * 1000 + c] = acc[i][j];
        }
    }
}

__global__ void k_fcg1_red(const float* __restrict__ part, const float* __restrict__ bias,
                           float* __restrict__ out) {
    int idx = blockIdx.x * 256 + threadIdx.x;
    if (idx >= GG * 1000) return;
    float s = 0.f;
#pragma unroll
    for (int k = 0; k < F1KS; ++k) s += part[(size_t)k * GG * 1000 + idx];
    int n = idx % 1000;
    float v = s + bias[n];
    out[idx] = (v >= 0.f) ? v : 0.01f * v;
}

// ---------------- fcg2 ----------------

__global__ __launch_bounds__(256) void k_fcg2(const float* __restrict__ in, const float* __restrict__ W,
                                              const float* __restrict__ b, float* __restrict__ out) {
    __shared__ float part[4][64];
    int g = blockIdx.x;
    int o = threadIdx.x & 63, p = threadIdx.x >> 6;
    const float* row = in + (size_t)g * 1000;
    float acc = 0.f;
    for (int k = p * 250; k < (p + 1) * 250; ++k) acc += row[k] * W[k * 64 + o];
    part[p][o] = acc;
    __syncthreads();
    if (p == 0) out[(size_t)g * 64 + o] = part[0][o] + part[1][o] + part[2][o] + part[3][o] + b[o];
}

// ---------------- final head ----------------

__global__ __launch_bounds__(256) void k_final(
    const float* __restrict__ b1, const float* __restrict__ b2, const float* __restrict__ target,
    const float* __restrict__ fcxtW, const float* __restrict__ fcxtb,
    const float* __restrict__ fc1W, const float* __restrict__ fc1b,
    const float* __restrict__ fc2W, const float* __restrict__ fc2b,
    const float* __restrict__ outW, const float* __restrict__ outb,
    float* __restrict__ out) {
    __shared__ float xc[256];
    __shared__ float xt2[128];
    __shared__ float y1[128];
    __shared__ float y2[32];
    int g = blockIdx.x, t = threadIdx.x;
    if (t < 64) xc[t] = b1[(size_t)g * 64 + t];
    else if (t < 128) xc[t] = b2[(size_t)g * 64 + (t - 64)];
    {
        int c = t & 127, p = t >> 7;
        float acc = 0.f;
        const float* trow = target + (size_t)g * 1000;
        for (int k = p * 500; k < (p + 1) * 500; ++k) acc += trow[k] * fcxtW[k * 128 + c];
        if (p == 1) xt2[c] = acc;
        __syncthreads();
        if (p == 0) xc[128 + c] = acc + xt2[c] + fcxtb[c];
    }
    __syncthreads();
    if (t < 128) {
        float acc = 0.f;
        for (int k = 0; k < 256; ++k) acc += xc[k] * fc1W[k * 128 + t];
        acc += fc1b[t];
        y1[t] = (acc >= 0.f) ? acc : 0.01f * acc;
    }
    __syncthreads();
    if (t < 32) {
        float acc = 0.f;
        for (int k = 0; k < 128; ++k) acc += y1[k] * fc2W[k * 32 + t];
        acc += fc2b[t];
        y2[t] = (acc >= 0.f) ? acc : 0.01f * acc;
    }
    __syncthreads();
    if (t == 0) {
        float acc = 0.f;
        for (int k = 0; k < 32; ++k) acc += y2[k] * outW[k];
        out[g] = acc + outb[0];
    }
}

// ---------------- host launch ----------------

extern "C" void kernel_launch(void* const* d_in, const int* in_sizes, int n_in,
                              void* d_out, int out_size, void* d_ws, size_t ws_size,
                              hipStream_t stream) {
    (void)in_sizes; (void)n_in; (void)out_size; (void)ws_size;

    size_t off = 0;
    auto alloc = [&](size_t bytes) -> void* {
        void* p = (char*)d_ws + off;
        off += (bytes + 255) & ~(size_t)255;
        return p;
    };
    char* regionA = (char*)alloc((size_t)2 * NN * KP * 2);
    char* regionB = (char*)alloc((size_t)2 * NN * KP * 2);
    ushort_t* Bthi = (ushort_t*)alloc((size_t)KP * KP * 2);
    ushort_t* Btlo = (ushort_t*)alloc((size_t)KP * KP * 2);
    float* a_s    = (float*)alloc((size_t)NN * HH * 4);
    float* a_d    = (float*)alloc((size_t)NN * HH * 4);
    int*   deg    = (int*)alloc((size_t)NN * 4);
    int*   offs   = (int*)alloc((size_t)(NN + 1) * 4);
    int*   cursor = (int*)alloc((size_t)NN * 4);
    int*   csr    = (int*)alloc((size_t)EPRIME * 4);
    float* dinv   = (float*)alloc((size_t)NN * 4);
    int*   gstart = (int*)alloc((size_t)GG * 4);
    int*   gend   = (int*)alloc((size_t)GG * 4);
    int*   bsum   = (int*)alloc((size_t)128 * 4);
    float* gpool  = (float*)alloc((size_t)GG * 2 * HFD * 4);
    float* fc1out = (float*)alloc((size_t)GG * 1000 * 4);
    float* bout   = (float*)alloc((size_t)2 * GG * 64 * 4);

    // overlays
    unsigned* h0pk = (unsigned*)regionA;                     // packed (hi|lo<<16) [NN][KP]
    float*    h2f  = (float*)regionA;                        // after h0 is dead
    float*    f1part = (float*)regionA;                      // after h2 is dead
    ushort_t* xhi  = (ushort_t*)regionB;
    ushort_t* xlo  = (ushort_t*)regionB + (size_t)NN * 128;
    ushort_t* h1hi = (ushort_t*)regionB;                     // after x is dead
    ushort_t* h1lo = (ushort_t*)regionB + (size_t)NN * KP;
    float*    hgcn = (float*)regionB;                        // after h1 is dead

    const float* target = (const float*)d_in[6];
    const int NRB = cdiv(NN, 128);        // 157 row blocks
    const int NCB = KP / 128;             // 9 col blocks

    for (int b = 0; b < 2; ++b) {
        const float* x     = (const float*)d_in[b ? 3 : 0];
        const int*   ei    = (const int*)d_in[b ? 4 : 1];
        const int*   batch = (const int*)d_in[b ? 5 : 2];
        int pb = 7 + b * 10;
        const float* gatW    = (const float*)d_in[pb + 0];
        const float* att_src = (const float*)d_in[pb + 1];
        const float* att_dst = (const float*)d_in[pb + 2];
        const float* gatb    = (const float*)d_in[pb + 3];
        const float* gcnW    = (const float*)d_in[pb + 4];
        const float* gcnb    = (const float*)d_in[pb + 5];
        const float* f1W     = (const float*)d_in[pb + 6];
        const float* f1b     = (const float*)d_in[pb + 7];
        const float* f2W     = (const float*)d_in[pb + 8];
        const float* f2b     = (const float*)d_in[pb + 9];

        // CSR
        hipLaunchKernelGGL(k_init, dim3(cdiv(NN, 256)), dim3(256), 0, stream, deg, gstart, gend);
        hipLaunchKernelGGL(k_count, dim3(cdiv(EE, 256)), dim3(256), 0, stream, ei, deg);
        hipLaunchKernelGGL(k_scan1, dim3(NSCB), dim3(256), 0, stream, deg, offs, bsum);
        hipLaunchKernelGGL(k_scan2, dim3(1), dim3(128), 0, stream, bsum);
        hipLaunchKernelGGL(k_scan3prep, dim3(NSCB), dim3(256), 0, stream,
                           offs, bsum, cursor, deg, dinv, batch, gstart, gend);
        hipLaunchKernelGGL(k_fill, dim3(cdiv(EPRIME, 256)), dim3(256), 0, stream, ei, cursor, csr);

        // x -> split (regionB), gatW -> transpose split
        hipLaunchKernelGGL(k_split_x, dim3(cdiv(NN * 128, 256)), dim3(256), 0, stream, x, xhi, xlo);
        hipLaunchKernelGGL(k_tsplitT, dim3(128 / 64, KP / 64), dim3(256), 0, stream,
                           gatW, FF, HFD, 128, Bthi, Btlo);

        // h0 = x @ gatW -> packed (regionA). ksteps=4 (Kpad=128)
        hipLaunchKernelGGL((mfma_gemm<1>), dim3(NRB * NCB), dim3(256), 0, stream,
                           xhi, xlo, Bthi, Btlo, 128, 128, NN, HFD, 4, NCB,
                           (float*)nullptr, 0, h0pk, KP);

        // attention logits
        hipLaunchKernelGGL(k_att, dim3(cdiv(NN * HH, 256)), dim3(256), 0, stream,
                           h0pk, att_src, att_dst, a_s, a_d);

        // GAT aggregate -> h1 split (regionB)
        hipLaunchKernelGGL(gat_agg, dim3(cdiv(NN, 4)), dim3(256), 0, stream,
                           h0pk, a_s, a_d, offs, csr, gatb, h1hi, h1lo);

        // gcnW -> transpose split
        hipLaunchKernelGGL(k_tsplitT, dim3(KP / 64, KP / 64), dim3(256), 0, stream,
                           gcnW, HFD, HFD, KP, Bthi, Btlo);

        // h2 = h1 @ gcnW -> fp32 (regionA). ksteps=36
        hipLaunchKernelGGL((mfma_gemm<0>), dim3(NRB * NCB), dim3(256), 0, stream,
                           h1hi, h1lo, Bthi, Btlo, KP, KP, NN, HFD, KP / 32, NCB,
                           h2f, HFD, (unsigned*)nullptr, 0);

        // GCN aggregate -> hgcn (regionB)
        hipLaunchKernelGGL(gcn_agg, dim3(cdiv(NN, 4)), dim3(256), 0, stream,
                           h2f, offs, csr, dinv, gcnb, hgcn);

        // pooling
        hipLaunchKernelGGL(k_pool, dim3(GG, 5), dim3(64), 0, stream, hgcn, gstart, gend, gpool);

        // fcg1 split-K
        hipLaunchKernelGGL(k_fcg1_part, dim3(16, 2, F1KS), dim3(256), 0, stream,
                           gpool, f1W, f1part);
        hipLaunchKernelGGL(k_fcg1_red, dim3(cdiv(GG * 1000, 256)), dim3(256), 0, stream,
                           f1part, f1b, fc1out);

        // fcg2
        hipLaunchKernelGGL(k_fcg2, dim3(GG), dim3(256), 0, stream,
                           fc1out, f2W, f2b, bout + (size_t)b * GG * 64);
    }

    hipLaunchKernelGGL(k_final, dim3(GG), dim3(256), 0, stream,
                       bout, bout + (size_t)GG * 64, target,
                       (const float*)d_in[27], (const float*)d_in[28],
                       (const float*)d_in[29], (const float*)d_in[30],
                       (const float*)d_in[31], (const float*)d_in[32],
                       (const float*)d_in[33], (const float*)d_in[34],
                       (float*)d_out);
}